// Round 6
// baseline (423.078 us; speedup 1.0000x reference)
//
#include <hip/hip_runtime.h>
#include <math.h>

#define BB 8
#define CC 64
#define HH 128
#define WW 128
#define EE 8
#define OO 64
#define HID 128
#define GATEC 96
#define NP 8     // patches per spatial dim
#define PP 16    // patch size

typedef __attribute__((ext_vector_type(8))) short bf16x8;
typedef __attribute__((ext_vector_type(4))) float f32x4;

static __device__ __forceinline__ unsigned short f2bf(float f) {
  unsigned int u = __builtin_bit_cast(unsigned int, f);
  unsigned int r = (u + 0x7FFFu + ((u >> 16) & 1u)) >> 16;   // RNE
  return (unsigned short)r;
}

// ---------------- Kernel A: router gates (f32) ----------------
__global__ __launch_bounds__(256) void gate_kernel(
    const float* __restrict__ x,
    const float* __restrict__ W1, const float* __restrict__ b1,
    const float* __restrict__ W2, const float* __restrict__ b2,
    float* __restrict__ probs) {
  int blk = blockIdx.x;        // b*64 + pi*8 + pj
  int b  = blk >> 6;
  int pi = (blk >> 3) & 7;
  int pj = blk & 7;
  int t  = threadIdx.x;

  __shared__ float ps[256];
  __shared__ float g[GATEC];
  __shared__ float hbuf[HID];
  __shared__ float lg[EE];

  {
    int c = t >> 2, q = t & 3;
    const float* xb = x + ((size_t)(b * CC + c) * HH + pi * PP + q * 4) * WW + pj * PP;
    float s = 0.f;
    for (int r = 0; r < 4; ++r)
      for (int col = 0; col < PP; ++col)
        s += xb[r * WW + col];
    ps[t] = s;
  }
  __syncthreads();
  if (t < CC) {
    g[t] = (ps[4*t] + ps[4*t+1] + ps[4*t+2] + ps[4*t+3]) * (1.f / 256.f);
  } else if (t < CC + 32) {
    int k = t - CC;
    int fi = k & 7, kind = k >> 3;
    float freq  = (float)(1 << fi);
    float coord = (kind < 2) ? ((pi + 0.5f) / 8.f) : ((pj + 0.5f) / 8.f);
    float a = 6.28318530717958647692f * freq * coord;
    g[t] = (kind & 1) ? cosf(a) : sinf(a);
  }
  __syncthreads();
  if (t < HID) {
    float acc = b1[t];
    const float* w = W1 + (size_t)t * GATEC;
    for (int c = 0; c < GATEC; ++c) acc += w[c] * g[c];
    hbuf[t] = fmaxf(acc, 0.f);
  }
  __syncthreads();
  if (t < EE) {
    float acc = b2[t];
    const float* w = W2 + (size_t)t * HID;
    for (int k = 0; k < HID; ++k) acc += w[k] * hbuf[k];
    lg[t] = acc;
  }
  __syncthreads();
  if (t < EE) {
    float m = lg[0];
    for (int e = 1; e < EE; ++e) m = fmaxf(m, lg[e]);
    float sum = 0.f;
    for (int e = 0; e < EE; ++e) sum += expf(lg[e] - m);
    probs[((size_t)(b * EE + t) * NP + pi) * NP + pj] = expf(lg[t] - m) / sum;
  }
}

// ---------------- Kernel P: pack weights f32 [e][o][c][3][3] -> bf16 [e][t][o][c] ---
__global__ __launch_bounds__(256) void pack_kernel(
    const float* __restrict__ We, unsigned short* __restrict__ wp) {
  int idx = blockIdx.x * 256 + threadIdx.x;
  if (idx >= EE * 9 * OO * CC) return;
  int c  = idx & 63;
  int o  = (idx >> 6) & 63;
  int et = idx >> 12;            // e*9 + t
  int t  = et % 9;
  int e  = et / 9;
  float v = We[(((size_t)(e * OO + o) * CC) + c) * 9 + t];
  wp[idx] = f2bf(v);
}

// ---------------- Kernel B: MFMA expert conv + gated combine ----------------
// block = (b, half-patch: 8 rows x 16 cols). 4 waves; wave w = 64 o x 32 px
// (2 rows w*2,w*2+1 x 16 cols). Per iter: aw[4] (global), bx[2] (LDS), 8 MFMA.
// D = A(weights 16o x 32c) * B(x 32c x 16px): col=px=l&15, o=ot*16+kg*4+r.
// launch_bounds (256,3): cap ~170 total regs -> footprint ~156 fits, no spill;
// 3 blocks/CU = 3 waves/SIMD. ((256,4) capped at 128 -> spilled; R5 lesson.)
__global__ __launch_bounds__(256, 3) void conv_moe(
    const float* __restrict__ x,
    const unsigned short* __restrict__ wp,   // [e][t][o][c] bf16, flat taps
    const float* __restrict__ be,
    const float* __restrict__ probs, float* __restrict__ out) {
  int bx0  = blockIdx.x;           // patch*2 + half
  int b    = blockIdx.y;
  int patch = bx0 >> 1, half = bx0 & 1;
  int pi = patch >> 3, pj = patch & 7;
  const int h0 = pi * PP + half * 8;   // first output row of this block (8 rows)
  const int w0 = pj * PP;

  int lane = threadIdx.x & 63;
  int wave = threadIdx.x >> 6;     // 0..3
  int px   = lane & 15;
  int kg   = lane >> 4;            // 0..3

  // halo: 10 rows x 18 cols x 64c bf16, chunk-of-8 16B slots,
  // slot-swizzled: lds[sp][(j ^ g)*16] = c-chunk j, g=(gr+gc)&7
  __shared__ bf16x8 xs_v[180 * 8];
  char* xs = (char*)xs_v;

  for (int i = 0; i < 6; ++i) {
    int unit = i * 256 + threadIdx.x;
    if (unit < 1440) {
      int sp = unit % 180;
      int j  = unit / 180;             // content chunk 0..7 (c = j*8..j*8+7)
      int r = sp / 18, col = sp % 18;
      int gr = h0 + r - 1, gc = w0 + col - 1;
      bf16x8 v;
      if (gr >= 0 && gr < HH && gc >= 0 && gc < WW) {
        const float* xb = x + ((size_t)(b * CC + j * 8) * HH + gr) * WW + gc;
#pragma unroll
        for (int q = 0; q < 8; ++q) v[q] = (short)f2bf(xb[(size_t)q * HH * WW]);
      } else {
#pragma unroll
        for (int q = 0; q < 8; ++q) v[q] = 0;
      }
      int g = (gr + gc) & 7;
      *(bf16x8*)(xs + sp * 128 + ((j ^ g) & 7) * 16) = v;
    }
  }
  __syncthreads();

  // per-lane weight offset inside a 4096-elem tap block: (o16=px)*64 + kg*8
  const unsigned short* wlane = wp + px * CC + kg * 8;
  const int rowbase = wave * 2;
  const char* xrow = xs + (rowbase * 18 + px) * 128;
  const int gl = h0 + w0 - 2 + rowbase + px;   // g = (gl + pt+dy+dx)&7

  f32x4 outacc[4][2];
#pragma unroll
  for (int ot = 0; ot < 4; ++ot)
#pragma unroll
    for (int pt = 0; pt < 2; ++pt) outacc[ot][pt] = (f32x4)(0.f);

  bf16x8 awc[4], awn[4];
#pragma unroll
  for (int ot = 0; ot < 4; ++ot)               // preload n=0 (tap 0, ks 0)
    awc[ot] = *(const bf16x8*)(wlane + ot * 1024);

  for (int e = 0; e < EE; ++e) {
    f32x4 acc[4][2];
#pragma unroll
    for (int ot = 0; ot < 4; ++ot)
#pragma unroll
      for (int pt = 0; pt < 2; ++pt) acc[ot][pt] = (f32x4)(0.f);

    const unsigned short* wbase_e = wlane + (size_t)e * 9 * 4096;

#pragma unroll
    for (int sub = 0; sub < 18; ++sub) {
      const int t9 = sub >> 1, ks = sub & 1;
      const int dy = t9 / 3, dx = t9 % 3;
      // ---- prefetch weights for iteration n+1 (crosses e-boundary naturally) ----
      const int ntap = (sub + 1) >> 1, nks = (sub + 1) & 1;
      if (sub < 17 || e < 7) {
#pragma unroll
        for (int ot = 0; ot < 4; ++ot)
          awn[ot] = *(const bf16x8*)(wbase_e + ntap * 4096 + ot * 1024 + nks * 32);
      }
      // ---- bx from LDS ----
      bf16x8 bxv[2];
#pragma unroll
      for (int pt = 0; pt < 2; ++pt) {
        int g = (gl + pt + dy + dx) & 7;
        int m = ks * 4 + kg;
        bxv[pt] = *(const bf16x8*)(xrow + ((pt + dy) * 18 + dx) * 128 + ((m ^ g) & 7) * 16);
      }
      // ---- 8 MFMA ----
#pragma unroll
      for (int ot = 0; ot < 4; ++ot)
#pragma unroll
        for (int pt = 0; pt < 2; ++pt)
          acc[ot][pt] = __builtin_amdgcn_mfma_f32_16x16x32_bf16(
              awc[ot], bxv[pt], acc[ot][pt], 0, 0, 0);
#pragma unroll
      for (int ot = 0; ot < 4; ++ot) awc[ot] = awn[ot];
    }

    // epilogue: bias + relu + gate-weighted accumulate
    float gt = probs[((size_t)(b * EE + e) * NP + pi) * NP + pj];
#pragma unroll
    for (int ot = 0; ot < 4; ++ot) {
      f32x4 bias = *(const f32x4*)(be + e * OO + ot * 16 + kg * 4);
#pragma unroll
      for (int pt = 0; pt < 2; ++pt) {
#pragma unroll
        for (int r = 0; r < 4; ++r)
          outacc[ot][pt][r] += gt * fmaxf(acc[ot][pt][r] + bias[r], 0.f);
      }
    }
  }

  // ---- store: lane holds o = ot*16+kg*4+r, col = px; NT to spare L2 ----
#pragma unroll
  for (int ot = 0; ot < 4; ++ot) {
#pragma unroll
    for (int pt = 0; pt < 2; ++pt) {
      int o = ot * 16 + kg * 4;
      int h = h0 + rowbase + pt;
      float* op = out + ((size_t)(b * OO + o) * HH + h) * WW + w0 + px;
#pragma unroll
      for (int r = 0; r < 4; ++r)
        __builtin_nontemporal_store(outacc[ot][pt][r], op + (size_t)r * HH * WW);
    }
  }
}

extern "C" void kernel_launch(void* const* d_in, const int* in_sizes, int n_in,
                              void* d_out, int out_size, void* d_ws, size_t ws_size,
                              hipStream_t stream) {
  const float* x  = (const float*)d_in[0];
  const float* We = (const float*)d_in[1];
  const float* be = (const float*)d_in[2];
  const float* W1 = (const float*)d_in[3];
  const float* b1 = (const float*)d_in[4];
  const float* W2 = (const float*)d_in[5];
  const float* b2 = (const float*)d_in[6];
  float* out = (float*)d_out;

  float* probs = (float*)d_ws;                                  // 16 KB
  unsigned short* wpk = (unsigned short*)((char*)d_ws + 16384); // 576 KB bf16 packed weights

  gate_kernel<<<dim3(BB * NP * NP), dim3(256), 0, stream>>>(x, W1, b1, W2, b2, probs);
  pack_kernel<<<dim3((EE * 9 * OO * CC + 255) / 256), dim3(256), 0, stream>>>(We, wpk);
  conv_moe<<<dim3(2 * NP * NP, BB), dim3(256), 0, stream>>>(x, wpk, be, probs, out);
}

// Round 7
// 103.716 us; speedup vs baseline: 4.0792x; 4.0792x over previous
//
#include <hip/hip_runtime.h>
#include <math.h>

#define BB 8
#define CC 64
#define HH 128
#define WW 128
#define EE 8
#define OO 64
#define HID 128
#define GATEC 96
#define NP 8     // patches per spatial dim
#define PP 16    // patch size

typedef __attribute__((ext_vector_type(8))) short bf16x8;
typedef __attribute__((ext_vector_type(4))) float f32x4;

static __device__ __forceinline__ unsigned short f2bf(float f) {
  unsigned int u = __builtin_bit_cast(unsigned int, f);
  unsigned int r = (u + 0x7FFFu + ((u >> 16) & 1u)) >> 16;   // RNE
  return (unsigned short)r;
}

static __device__ __forceinline__ void gll16(const void* g, void* l) {
  __builtin_amdgcn_global_load_lds(
      (const __attribute__((address_space(1))) void*)g,
      (__attribute__((address_space(3))) void*)l, 16, 0, 0);
}

// ---------------- Kernel A: router gates (f32) ----------------
__global__ __launch_bounds__(256) void gate_kernel(
    const float* __restrict__ x,
    const float* __restrict__ W1, const float* __restrict__ b1,
    const float* __restrict__ W2, const float* __restrict__ b2,
    float* __restrict__ probs) {
  int blk = blockIdx.x;        // b*64 + pi*8 + pj
  int b  = blk >> 6;
  int pi = (blk >> 3) & 7;
  int pj = blk & 7;
  int t  = threadIdx.x;

  __shared__ float ps[256];
  __shared__ float g[GATEC];
  __shared__ float hbuf[HID];
  __shared__ float lg[EE];

  {
    int c = t >> 2, q = t & 3;
    const float* xb = x + ((size_t)(b * CC + c) * HH + pi * PP + q * 4) * WW + pj * PP;
    float s = 0.f;
    for (int r = 0; r < 4; ++r)
      for (int col = 0; col < PP; ++col)
        s += xb[r * WW + col];
    ps[t] = s;
  }
  __syncthreads();
  if (t < CC) {
    g[t] = (ps[4*t] + ps[4*t+1] + ps[4*t+2] + ps[4*t+3]) * (1.f / 256.f);
  } else if (t < CC + 32) {
    int k = t - CC;
    int fi = k & 7, kind = k >> 3;
    float freq  = (float)(1 << fi);
    float coord = (kind < 2) ? ((pi + 0.5f) / 8.f) : ((pj + 0.5f) / 8.f);
    float a = 6.28318530717958647692f * freq * coord;
    g[t] = (kind & 1) ? cosf(a) : sinf(a);
  }
  __syncthreads();
  if (t < HID) {
    float acc = b1[t];
    const float* w = W1 + (size_t)t * GATEC;
    for (int c = 0; c < GATEC; ++c) acc += w[c] * g[c];
    hbuf[t] = fmaxf(acc, 0.f);
  }
  __syncthreads();
  if (t < EE) {
    float acc = b2[t];
    const float* w = W2 + (size_t)t * HID;
    for (int k = 0; k < HID; ++k) acc += w[k] * hbuf[k];
    lg[t] = acc;
  }
  __syncthreads();
  if (t < EE) {
    float m = lg[0];
    for (int e = 1; e < EE; ++e) m = fmaxf(m, lg[e]);
    float sum = 0.f;
    for (int e = 0; e < EE; ++e) sum += expf(lg[e] - m);
    probs[((size_t)(b * EE + t) * NP + pi) * NP + pj] = expf(lg[t] - m) / sum;
  }
}

// ---- Kernel P: pack weights f32 [e][o][c][3][3] -> bf16 [tap=e*9+t][o][c],
//      with the LDS bank swizzle baked in: within a tap, elem (o,c) lands at
//      o*64 + (((c>>3) ^ (o&7))<<3) + (c&7).  A linear global->LDS copy of a
//      tap then yields the conflict-free layout directly.
__global__ __launch_bounds__(256) void pack_kernel(
    const float* __restrict__ We, unsigned short* __restrict__ wp) {
  int idx = blockIdx.x * 256 + threadIdx.x;
  if (idx >= EE * 9 * OO * CC) return;
  int c  = idx & 63;
  int o  = (idx >> 6) & 63;
  int et = idx >> 12;            // e*9 + t
  int t  = et % 9;
  int e  = et / 9;
  float v = We[(((size_t)(e * OO + o) * CC) + c) * 9 + t];
  int dst = (et << 12) + (o << 6) + ((((c >> 3) ^ (o & 7)) << 3) | (c & 7));
  wp[dst] = f2bf(v);
}

// ---------------- Kernel B: MFMA expert conv + gated combine ----------------
// block = (b, region 8 rows x 32 cols) = two half-patches side by side.
// 4 waves; wave w = 64 o x (2 rows x 32 cols).  Weights stream through LDS,
// double-buffered chunks of 2 taps (16 KB) issued 1 chunk ahead via
// global_load_lds; x tile (10x34x64 bf16) staged once.
// Per sub (tap,ks): 4 aw + 4 bx ds_read_b128 -> 16 MFMA.
__global__ __launch_bounds__(256, 2) void conv_moe(
    const float* __restrict__ x,
    const unsigned short* __restrict__ wp,   // packed [tap][o][c-swz] bf16
    const float* __restrict__ be,
    const float* __restrict__ probs, float* __restrict__ out) {
  int bx0 = blockIdx.x;            // rg*4 + cg
  int b   = blockIdx.y;
  int rg = bx0 >> 2, cg = bx0 & 3;
  const int h0 = rg * 8, w0 = cg * 32;
  const int pi = rg >> 1;          // patch row
  const int pj0 = cg * 2;          // left patch col

  int lane = threadIdx.x & 63;
  int wave = threadIdx.x >> 6;     // 0..3
  int px   = lane & 15;
  int kg   = lane >> 4;            // 0..3

  __shared__ char xs[340 * 128];   // x tile: [sp=r*34+col][64c bf16], swizzled
  __shared__ char wb[2][16384];    // weight chunks: 2 taps each, double-buffered

  // ---- stage x tile (once) ----
  for (int idx = threadIdx.x; idx < 340 * 8; idx += 256) {
    int j  = idx / 340;            // c-chunk 0..7 (c = j*8..j*8+7)
    int sp = idx % 340;
    int r = sp / 34, col = sp % 34;
    int gr = h0 + r - 1, gc = w0 + col - 1;
    bf16x8 v;
    if (gr >= 0 && gr < HH && gc >= 0 && gc < WW) {
      const float* xb = x + ((size_t)(b * CC + j * 8) * HH + gr) * WW + gc;
#pragma unroll
      for (int q = 0; q < 8; ++q) v[q] = (short)f2bf(xb[(size_t)q * HH * WW]);
    } else {
#pragma unroll
      for (int q = 0; q < 8; ++q) v[q] = 0;
    }
    int g = (gr + gc) & 7;
    *(bf16x8*)(xs + sp * 128 + ((j ^ g) & 7) * 16) = v;
  }

  // ---- issue weight chunk 0 (taps 0,1) ----
  {
    const char* src = (const char*)wp + (size_t)(wave * 4) * 1024 + lane * 16;
    char* dst = &wb[0][(wave * 4) * 1024];
#pragma unroll
    for (int i = 0; i < 4; ++i)
      gll16(src + i * 1024, dst + i * 1024);
  }
  __syncthreads();   // x tile + chunk 0 ready

  f32x4 outacc[4][4], acc[4][4];   // [ot][f = rowp*2 + colhalf]
#pragma unroll
  for (int ot = 0; ot < 4; ++ot)
#pragma unroll
    for (int f = 0; f < 4; ++f) { outacc[ot][f] = (f32x4)(0.f); acc[ot][f] = (f32x4)(0.f); }

  const int gl = h0 + w0 - 2 + wave * 2 + px;   // swizzle phase base

  int t9 = 0, dy = 0, dx = 0, e = 0;
  for (int u = 0; u < 36; ++u) {
    int cur = u & 1;
    // ---- issue next chunk (consumed next iter; full iter of latency slack) ----
    if (u < 35) {
      const char* src = (const char*)wp + (size_t)(u + 1) * 16384 + (wave * 4) * 1024 + lane * 16;
      char* dst = &wb[cur ^ 1][(wave * 4) * 1024];
#pragma unroll
      for (int i = 0; i < 4; ++i)
        gll16(src + i * 1024, dst + i * 1024);
    }
    // ---- consume 2 taps from wb[cur] ----
#pragma unroll
    for (int ht = 0; ht < 2; ++ht) {
      const char* wt = &wb[cur][ht * 8192];
#pragma unroll
      for (int ks = 0; ks < 2; ++ks) {
        bf16x8 aw[4], bxv[4];
#pragma unroll
        for (int ot = 0; ot < 4; ++ot)
          aw[ot] = *(const bf16x8*)(wt + (ot * 16 + px) * 128 +
                                    ((((ks << 2) | kg) ^ (px & 7)) << 4));
#pragma unroll
        for (int f = 0; f < 4; ++f) {
          int rowp = f >> 1, ch = f & 1;
          int sp = (wave * 2 + rowp + dy) * 34 + ch * 16 + px + dx;
          int g  = (gl + rowp + dy + dx) & 7;
          bxv[f] = *(const bf16x8*)(xs + sp * 128 + (((((ks << 2) | kg) ^ g) & 7) << 4));
        }
#pragma unroll
        for (int ot = 0; ot < 4; ++ot)
#pragma unroll
          for (int f = 0; f < 4; ++f)
            acc[ot][f] = __builtin_amdgcn_mfma_f32_16x16x32_bf16(
                aw[ot], bxv[f], acc[ot][f], 0, 0, 0);
      }
      // ---- advance tap; expert epilogue on wrap ----
      if (++dx == 3) { dx = 0; ++dy; }
      if (++t9 == 9) {
        float gA = probs[((size_t)(b * EE + e) * NP + pi) * NP + pj0];
        float gB = probs[((size_t)(b * EE + e) * NP + pi) * NP + pj0 + 1];
#pragma unroll
        for (int ot = 0; ot < 4; ++ot) {
          f32x4 bias = *(const f32x4*)(be + e * OO + ot * 16 + kg * 4);
#pragma unroll
          for (int f = 0; f < 4; ++f) {
            float gt = (f & 1) ? gB : gA;
#pragma unroll
            for (int r = 0; r < 4; ++r) {
              outacc[ot][f][r] += gt * fmaxf(acc[ot][f][r] + bias[r], 0.f);
              acc[ot][f][r] = 0.f;
            }
          }
        }
        t9 = 0; dy = 0; dx = 0; ++e;
      }
    }
    __syncthreads();   // chunk u consumed by all; next-iter writes may proceed
  }

  // ---- store: lane holds o = ot*16+kg*4+r, col = w0 + ch*16 + px ----
#pragma unroll
  for (int ot = 0; ot < 4; ++ot) {
#pragma unroll
    for (int f = 0; f < 4; ++f) {
      int rowp = f >> 1, ch = f & 1;
      int o = ot * 16 + kg * 4;
      int h = h0 + wave * 2 + rowp;
      float* op = out + ((size_t)(b * OO + o) * HH + h) * WW + w0 + ch * 16 + px;
#pragma unroll
      for (int r = 0; r < 4; ++r)
        op[(size_t)r * HH * WW] = outacc[ot][f][r];
    }
  }
}

extern "C" void kernel_launch(void* const* d_in, const int* in_sizes, int n_in,
                              void* d_out, int out_size, void* d_ws, size_t ws_size,
                              hipStream_t stream) {
  const float* x  = (const float*)d_in[0];
  const float* We = (const float*)d_in[1];
  const float* be = (const float*)d_in[2];
  const float* W1 = (const float*)d_in[3];
  const float* b1 = (const float*)d_in[4];
  const float* W2 = (const float*)d_in[5];
  const float* b2 = (const float*)d_in[6];
  float* out = (float*)d_out;

  float* probs = (float*)d_ws;                                  // 16 KB
  unsigned short* wpk = (unsigned short*)((char*)d_ws + 16384); // 576 KB packed weights

  gate_kernel<<<dim3(BB * NP * NP), dim3(256), 0, stream>>>(x, W1, b1, W2, b2, probs);
  pack_kernel<<<dim3((EE * 9 * OO * CC + 255) / 256), dim3(256), 0, stream>>>(We, wpk);
  conv_moe<<<dim3(16 * 4, BB), dim3(256), 0, stream>>>(x, wpk, be, probs, out);
}

// Round 8
// 103.091 us; speedup vs baseline: 4.1039x; 1.0061x over previous
//
#include <hip/hip_runtime.h>
#include <math.h>

#define BB 8
#define CC 64
#define HH 128
#define WW 128
#define EE 8
#define OO 64
#define HID 128
#define GATEC 96
#define NP 8     // patches per spatial dim
#define PP 16    // patch size

typedef __attribute__((ext_vector_type(8))) short bf16x8;
typedef __attribute__((ext_vector_type(4))) float f32x4;

static __device__ __forceinline__ unsigned short f2bf(float f) {
  unsigned int u = __builtin_bit_cast(unsigned int, f);
  unsigned int r = (u + 0x7FFFu + ((u >> 16) & 1u)) >> 16;   // RNE
  return (unsigned short)r;
}

static __device__ __forceinline__ void gll16(const void* g, void* l) {
  __builtin_amdgcn_global_load_lds(
      (const __attribute__((address_space(1))) void*)g,
      (__attribute__((address_space(3))) void*)l, 16, 0, 0);
}

// ---------------- Kernel A+P fused: router gates + weight pack ----------------
// blocks 0..511: gate (b*64 + pi*8 + pj); blocks 512..1663: pack
__global__ __launch_bounds__(256) void prep_kernel(
    const float* __restrict__ x,
    const float* __restrict__ W1, const float* __restrict__ b1,
    const float* __restrict__ W2, const float* __restrict__ b2,
    const float* __restrict__ We,
    float* __restrict__ probs, unsigned short* __restrict__ wp) {
  __shared__ float ps[256];
  __shared__ float g[GATEC];
  __shared__ float hbuf[HID];
  __shared__ float lg[EE];

  if (blockIdx.x >= 512) {
    // ---- pack weights f32 [e][o][c][3][3] -> bf16 [tap=e*9+t][o][c-swz];
    // within a tap, (o,c) lands at o*64 + (((c>>3)^(o&7))<<3) + (c&7) so a
    // linear global->LDS copy of a tap yields the conflict-free layout.
    int idx = (blockIdx.x - 512) * 256 + threadIdx.x;
    if (idx < EE * 9 * OO * CC) {
      int c  = idx & 63;
      int o  = (idx >> 6) & 63;
      int et = idx >> 12;            // e*9 + t
      int t  = et % 9;
      int e  = et / 9;
      float v = We[(((size_t)(e * OO + o) * CC) + c) * 9 + t];
      int dst = (et << 12) + (o << 6) + ((((c >> 3) ^ (o & 7)) << 3) | (c & 7));
      wp[dst] = f2bf(v);
    }
    return;
  }

  int blk = blockIdx.x;        // b*64 + pi*8 + pj
  int b  = blk >> 6;
  int pi = (blk >> 3) & 7;
  int pj = blk & 7;
  int t  = threadIdx.x;

  {
    int c = t >> 2, q = t & 3;
    const float* xb = x + ((size_t)(b * CC + c) * HH + pi * PP + q * 4) * WW + pj * PP;
    float s = 0.f;
    for (int r = 0; r < 4; ++r)
      for (int col = 0; col < PP; ++col)
        s += xb[r * WW + col];
    ps[t] = s;
  }
  __syncthreads();
  if (t < CC) {
    g[t] = (ps[4*t] + ps[4*t+1] + ps[4*t+2] + ps[4*t+3]) * (1.f / 256.f);
  } else if (t < CC + 32) {
    int k = t - CC;
    int fi = k & 7, kind = k >> 3;
    float freq  = (float)(1 << fi);
    float coord = (kind < 2) ? ((pi + 0.5f) / 8.f) : ((pj + 0.5f) / 8.f);
    float a = 6.28318530717958647692f * freq * coord;
    g[t] = (kind & 1) ? cosf(a) : sinf(a);
  }
  __syncthreads();
  if (t < HID) {
    float acc = b1[t];
    const float* w = W1 + (size_t)t * GATEC;
    for (int c = 0; c < GATEC; ++c) acc += w[c] * g[c];
    hbuf[t] = fmaxf(acc, 0.f);
  }
  __syncthreads();
  if (t < EE) {
    float acc = b2[t];
    const float* w = W2 + (size_t)t * HID;
    for (int k = 0; k < HID; ++k) acc += w[k] * hbuf[k];
    lg[t] = acc;
  }
  __syncthreads();
  if (t < EE) {
    float m = lg[0];
    for (int e = 1; e < EE; ++e) m = fmaxf(m, lg[e]);
    float sum = 0.f;
    for (int e = 0; e < EE; ++e) sum += expf(lg[e] - m);
    probs[((size_t)(b * EE + t) * NP + pi) * NP + pj] = expf(lg[t] - m) / sum;
  }
}

// ---------------- Kernel B: MFMA expert conv + gated combine ----------------
// block = (b, region 8 rows x 32 cols); 4 waves; wave = 64 o x (2 rows x 32 cols).
// Weights stream through LDS (double-buffered 2-tap 16KB chunks via
// global_load_lds, issued 1 chunk ahead); x tile (10x34x64 bf16) staged once.
// NEW vs R7: sub-granularity software pipeline — operand regs double-buffered
// (A0/B0, A1/B1); sub n+1's 8 ds_reads issued BEFORE sub n's 16-MFMA cluster,
// so LDS and MFMA pipes run concurrently instead of alternating bursts.
__global__ __launch_bounds__(256, 2) void conv_moe(
    const float* __restrict__ x,
    const unsigned short* __restrict__ wp,   // packed [tap][o][c-swz] bf16
    const float* __restrict__ be,
    const float* __restrict__ probs, float* __restrict__ out) {
  int bx0 = blockIdx.x;            // rg*4 + cg
  int b   = blockIdx.y;
  int rg = bx0 >> 2, cg = bx0 & 3;
  const int h0 = rg * 8, w0 = cg * 32;
  const int pi = rg >> 1;          // patch row
  const int pj0 = cg * 2;          // left patch col

  int lane = threadIdx.x & 63;
  int wave = threadIdx.x >> 6;     // 0..3
  int px   = lane & 15;
  int kg   = lane >> 4;            // 0..3

  __shared__ char xs[340 * 128];   // x tile: [sp=r*34+col][64c bf16], swizzled
  __shared__ char wb[2][16384];    // weight chunks: 2 taps each, double-buffered

  // ---- issue weight chunk 0 first (DMA overlaps the x staging VALU) ----
  {
    const char* src = (const char*)wp + (size_t)(wave * 4) * 1024 + lane * 16;
    char* dst = &wb[0][(wave * 4) * 1024];
#pragma unroll
    for (int i = 0; i < 4; ++i)
      gll16(src + i * 1024, dst + i * 1024);
  }

  // ---- stage x tile (once) ----
  for (int idx = threadIdx.x; idx < 340 * 8; idx += 256) {
    int j  = idx / 340;            // c-chunk 0..7 (c = j*8..j*8+7)
    int sp = idx % 340;
    int r = sp / 34, col = sp % 34;
    int gr = h0 + r - 1, gc = w0 + col - 1;
    bf16x8 v;
    if (gr >= 0 && gr < HH && gc >= 0 && gc < WW) {
      const float* xb = x + ((size_t)(b * CC + j * 8) * HH + gr) * WW + gc;
#pragma unroll
      for (int q = 0; q < 8; ++q) v[q] = (short)f2bf(xb[(size_t)q * HH * WW]);
    } else {
#pragma unroll
      for (int q = 0; q < 8; ++q) v[q] = 0;
    }
    int g = (gr + gc) & 7;
    *(bf16x8*)(xs + sp * 128 + ((j ^ g) & 7) * 16) = v;
  }
  __syncthreads();   // x tile + chunk 0 ready

  f32x4 outacc[4][4], acc[4][4];   // [ot][f = rowp*2 + colhalf]
#pragma unroll
  for (int ot = 0; ot < 4; ++ot)
#pragma unroll
    for (int f = 0; f < 4; ++f) { outacc[ot][f] = (f32x4)(0.f); acc[ot][f] = (f32x4)(0.f); }

  const int gl = h0 + w0 - 2 + wave * 2 + px;   // swizzle phase base

#define LOADAW(dst, wt, ks)                                                     \
  {                                                                             \
    _Pragma("unroll")                                                           \
    for (int ot = 0; ot < 4; ++ot)                                              \
      dst[ot] = *(const bf16x8*)((wt) + (ot * 16 + px) * 128 +                  \
                                 (((((ks) << 2) | kg) ^ (px & 7)) << 4));       \
  }

#define LOADBX(dst, dy, dx, ks)                                                 \
  {                                                                             \
    _Pragma("unroll")                                                           \
    for (int f = 0; f < 4; ++f) {                                               \
      int rowp = f >> 1, ch = f & 1;                                            \
      int sp = (wave * 2 + rowp + (dy)) * 34 + ch * 16 + px + (dx);             \
      int slot = (((((ks) << 2) | kg) ^ (gl + rowp + (dy) + (dx))) & 7);        \
      dst[f] = *(const bf16x8*)(xs + sp * 128 + (slot << 4));                   \
    }                                                                           \
  }

#define MFMA16(A, B)                                                            \
  {                                                                             \
    __builtin_amdgcn_s_setprio(1);                                              \
    _Pragma("unroll")                                                           \
    for (int ot = 0; ot < 4; ++ot)                                              \
      _Pragma("unroll")                                                         \
      for (int f = 0; f < 4; ++f)                                               \
        acc[ot][f] = __builtin_amdgcn_mfma_f32_16x16x32_bf16(A[ot], B[f],       \
                                                             acc[ot][f], 0, 0, 0); \
    __builtin_amdgcn_s_setprio(0);                                              \
  }

#define EPILOGUE(eidx)                                                          \
  {                                                                             \
    float gA = probs[((size_t)(b * EE + (eidx)) * NP + pi) * NP + pj0];         \
    float gB = probs[((size_t)(b * EE + (eidx)) * NP + pi) * NP + pj0 + 1];     \
    _Pragma("unroll")                                                           \
    for (int ot = 0; ot < 4; ++ot) {                                            \
      f32x4 bias = *(const f32x4*)(be + (eidx) * OO + ot * 16 + kg * 4);        \
      _Pragma("unroll")                                                         \
      for (int f = 0; f < 4; ++f) {                                             \
        float gt = (f & 1) ? gB : gA;                                           \
        _Pragma("unroll")                                                       \
        for (int r = 0; r < 4; ++r) {                                           \
          outacc[ot][f][r] += gt * fmaxf(acc[ot][f][r] + bias[r], 0.f);         \
          acc[ot][f][r] = 0.f;                                                  \
        }                                                                       \
      }                                                                         \
    }                                                                           \
  }

  bf16x8 A0[4], B0[4], A1[4], B1[4];
  int e = 0, t9A = 0, dyA = 0, dxA = 0;

  for (int u = 0; u < 36; ++u) {
    int cur = u & 1;
    // ---- issue next weight chunk (consumed next iter; full iter of slack) ----
    if (u < 35) {
      const char* src = (const char*)wp + (size_t)(u + 1) * 16384 + (wave * 4) * 1024 + lane * 16;
      char* dst = &wb[cur ^ 1][(wave * 4) * 1024];
#pragma unroll
      for (int i = 0; i < 4; ++i)
        gll16(src + i * 1024, dst + i * 1024);
    }
    // tap B (= tap A + 1) indices
    int t9B = t9A + 1, dyB = dyA, dxB = dxA + 1;
    if (dxB == 3) { dxB = 0; dyB += 1; }
    if (t9B == 9) { t9B = 0; dyB = 0; dxB = 0; }
    const char* wtA = &wb[cur][0];
    const char* wtB = &wb[cur][8192];

    // ---- pipelined subs: reads of sub n+1 fly under MFMAs of sub n ----
    LOADAW(A0, wtA, 0); LOADBX(B0, dyA, dxA, 0);     // R(s0)
    LOADAW(A1, wtA, 1); LOADBX(B1, dyA, dxA, 1);     // R(s1)
    MFMA16(A0, B0);                                  // M(s0)
    LOADAW(A0, wtB, 0); LOADBX(B0, dyB, dxB, 0);     // R(s2)
    MFMA16(A1, B1);                                  // M(s1)
    if (t9A == 8) { EPILOGUE(e); ++e; }              // expert ends on tap A
    LOADAW(A1, wtB, 1); LOADBX(B1, dyB, dxB, 1);     // R(s3)
    MFMA16(A0, B0);                                  // M(s2)
    MFMA16(A1, B1);                                  // M(s3)
    if (t9B == 8) { EPILOGUE(e); ++e; }              // expert ends on tap B

    // advance tap A by 2
    t9A = t9B + 1; dyA = dyB; dxA = dxB + 1;
    if (dxA == 3) { dxA = 0; dyA += 1; }
    if (t9A == 9) { t9A = 0; dyA = 0; dxA = 0; }
    __syncthreads();   // chunk consumed by all; next DMA writes may land
  }

  // ---- store: lane holds o = ot*16+kg*4+r, col = w0 + ch*16 + px ----
#pragma unroll
  for (int ot = 0; ot < 4; ++ot) {
#pragma unroll
    for (int f = 0; f < 4; ++f) {
      int rowp = f >> 1, ch = f & 1;
      int o = ot * 16 + kg * 4;
      int h = h0 + wave * 2 + rowp;
      float* op = out + ((size_t)(b * OO + o) * HH + h) * WW + w0 + ch * 16 + px;
#pragma unroll
      for (int r = 0; r < 4; ++r)
        op[(size_t)r * HH * WW] = outacc[ot][f][r];
    }
  }
#undef LOADAW
#undef LOADBX
#undef MFMA16
#undef EPILOGUE
}

extern "C" void kernel_launch(void* const* d_in, const int* in_sizes, int n_in,
                              void* d_out, int out_size, void* d_ws, size_t ws_size,
                              hipStream_t stream) {
  const float* x  = (const float*)d_in[0];
  const float* We = (const float*)d_in[1];
  const float* be = (const float*)d_in[2];
  const float* W1 = (const float*)d_in[3];
  const float* b1 = (const float*)d_in[4];
  const float* W2 = (const float*)d_in[5];
  const float* b2 = (const float*)d_in[6];
  float* out = (float*)d_out;

  float* probs = (float*)d_ws;                                  // 16 KB
  unsigned short* wpk = (unsigned short*)((char*)d_ws + 16384); // 576 KB packed weights

  prep_kernel<<<dim3(512 + (EE * 9 * OO * CC + 255) / 256), dim3(256), 0, stream>>>(
      x, W1, b1, W2, b2, We, probs, wpk);
  conv_moe<<<dim3(16 * 4, BB), dim3(256), 0, stream>>>(x, wpk, be, probs, out);
}

// Round 9
// 99.251 us; speedup vs baseline: 4.2627x; 1.0387x over previous
//
#include <hip/hip_runtime.h>
#include <math.h>

#define BB 8
#define CC 64
#define HH 128
#define WW 128
#define EE 8
#define OO 64
#define HID 128
#define GATEC 96
#define NP 8     // patches per spatial dim
#define PP 16    // patch size

typedef __attribute__((ext_vector_type(8))) short bf16x8;
typedef __attribute__((ext_vector_type(4))) float f32x4;

static __device__ __forceinline__ unsigned short f2bf(float f) {
  unsigned int u = __builtin_bit_cast(unsigned int, f);
  unsigned int r = (u + 0x7FFFu + ((u >> 16) & 1u)) >> 16;   // RNE
  return (unsigned short)r;
}

// ---------------- Kernel A+P fused: router gates + weight pack ----------------
// blocks 0..511: gate (b*64 + pi*8 + pj); blocks 512..1663: pack
// pack layout: per tap (=e*9+t), 8 chunks of 512 halfwords (1 KB), chunk
// i = ks*4+ot; within a chunk lane l=(kg*16+px) holds its 8 contiguous
// halfwords -> each A-fragment load is ONE fully-coalesced 1 KB
// global_load_dwordx4 per wave:  elem (o,c):
//   dst = tap*4096 + ((c>>5)*4 + (o>>4))*512 + (((c>>3)&3)*16 + (o&15))*8 + (c&7)
__global__ __launch_bounds__(256) void prep_kernel(
    const float* __restrict__ x,
    const float* __restrict__ W1, const float* __restrict__ b1,
    const float* __restrict__ W2, const float* __restrict__ b2,
    const float* __restrict__ We,
    float* __restrict__ probs, unsigned short* __restrict__ wp) {
  __shared__ float ps[256];
  __shared__ float g[GATEC];
  __shared__ float hbuf[HID];
  __shared__ float lg[EE];

  if (blockIdx.x >= 512) {
    int idx = (blockIdx.x - 512) * 256 + threadIdx.x;
    if (idx < EE * 9 * OO * CC) {
      int c  = idx & 63;
      int o  = (idx >> 6) & 63;
      int et = idx >> 12;            // e*9 + t
      int t  = et % 9;
      int e  = et / 9;
      float v = We[(((size_t)(e * OO + o) * CC) + c) * 9 + t];
      int dst = (et << 12) + (((c >> 5) * 4 + (o >> 4)) << 9)
              + ((((c >> 3) & 3) * 16 + (o & 15)) << 3) + (c & 7);
      wp[dst] = f2bf(v);
    }
    return;
  }

  int blk = blockIdx.x;        // b*64 + pi*8 + pj
  int b  = blk >> 6;
  int pi = (blk >> 3) & 7;
  int pj = blk & 7;
  int t  = threadIdx.x;

  {
    int c = t >> 2, q = t & 3;
    const float* xb = x + ((size_t)(b * CC + c) * HH + pi * PP + q * 4) * WW + pj * PP;
    float s = 0.f;
    for (int r = 0; r < 4; ++r)
      for (int col = 0; col < PP; ++col)
        s += xb[r * WW + col];
    ps[t] = s;
  }
  __syncthreads();
  if (t < CC) {
    g[t] = (ps[4*t] + ps[4*t+1] + ps[4*t+2] + ps[4*t+3]) * (1.f / 256.f);
  } else if (t < CC + 32) {
    int k = t - CC;
    int fi = k & 7, kind = k >> 3;
    float freq  = (float)(1 << fi);
    float coord = (kind < 2) ? ((pi + 0.5f) / 8.f) : ((pj + 0.5f) / 8.f);
    float a = 6.28318530717958647692f * freq * coord;
    g[t] = (kind & 1) ? cosf(a) : sinf(a);
  }
  __syncthreads();
  if (t < HID) {
    float acc = b1[t];
    const float* w = W1 + (size_t)t * GATEC;
    for (int c = 0; c < GATEC; ++c) acc += w[c] * g[c];
    hbuf[t] = fmaxf(acc, 0.f);
  }
  __syncthreads();
  if (t < EE) {
    float acc = b2[t];
    const float* w = W2 + (size_t)t * HID;
    for (int k = 0; k < HID; ++k) acc += w[k] * hbuf[k];
    lg[t] = acc;
  }
  __syncthreads();
  if (t < EE) {
    float m = lg[0];
    for (int e = 1; e < EE; ++e) m = fmaxf(m, lg[e]);
    float sum = 0.f;
    for (int e = 0; e < EE; ++e) sum += expf(lg[e] - m);
    probs[((size_t)(b * EE + t) * NP + pi) * NP + pj] = expf(lg[t] - m) / sum;
  }
}

// ---------------- Kernel B: MFMA expert conv + gated combine ----------------
// block = (b, region 8 rows x 32 cols); 4 waves; wave = 64 o x (2 rows x 32 cols).
// NEW vs R8: weights stream L2 -> REGISTERS (1-tap-deep dbuf, one coalesced
// 1 KB global load per fragment) -- no weight LDS, no main-loop barriers.
// LDS holds only the read-only x tile (staged once, single barrier). Waves
// free-run, self-paced by register dependencies (AITER-style interleave).
__global__ __launch_bounds__(256, 2) void conv_moe(
    const float* __restrict__ x,
    const unsigned short* __restrict__ wp,   // packed [tap][8 x 1KB chunks] bf16
    const float* __restrict__ be,
    const float* __restrict__ probs, float* __restrict__ out) {
  int bx0 = blockIdx.x;            // rg*4 + cg
  int b   = blockIdx.y;
  int rg = bx0 >> 2, cg = bx0 & 3;
  const int h0 = rg * 8, w0 = cg * 32;
  const int pi = rg >> 1;          // patch row
  const int pj0 = cg * 2;          // left patch col

  int lane = threadIdx.x & 63;
  int wave = threadIdx.x >> 6;     // 0..3
  int px   = lane & 15;
  int kg   = lane >> 4;            // 0..3

  __shared__ char xs[340 * 128];   // x tile: [sp=r*34+col][64c bf16], swizzled

  // ---- stage x tile (once) ----
  for (int idx = threadIdx.x; idx < 340 * 8; idx += 256) {
    int j  = idx / 340;            // c-chunk 0..7 (c = j*8..j*8+7)
    int sp = idx % 340;
    int r = sp / 34, col = sp % 34;
    int gr = h0 + r - 1, gc = w0 + col - 1;
    bf16x8 v;
    if (gr >= 0 && gr < HH && gc >= 0 && gc < WW) {
      const float* xb = x + ((size_t)(b * CC + j * 8) * HH + gr) * WW + gc;
#pragma unroll
      for (int q = 0; q < 8; ++q) v[q] = (short)f2bf(xb[(size_t)q * HH * WW]);
    } else {
#pragma unroll
      for (int q = 0; q < 8; ++q) v[q] = 0;
    }
    int g = (gr + gc) & 7;
    *(bf16x8*)(xs + sp * 128 + ((j ^ g) & 7) * 16) = v;
  }
  __syncthreads();   // ONLY barrier: xs is read-only below

  f32x4 outacc[4][4], acc[4][4];   // [ot][f = rowp*2 + colhalf]
#pragma unroll
  for (int ot = 0; ot < 4; ++ot)
#pragma unroll
    for (int f = 0; f < 4; ++f) { outacc[ot][f] = (f32x4)(0.f); acc[ot][f] = (f32x4)(0.f); }

  const int gl = h0 + w0 - 2 + wave * 2 + px;   // swizzle phase base

  // per-lane weight pointer: lane's 16B within each 1KB chunk
  const unsigned short* wq = wp + lane * 8;

  // aw bank = 8 fragments (i = ks*4 + ot), each one coalesced 1KB wave-load
#define LOADW(bank, tap)                                                        \
  {                                                                             \
    const unsigned short* wt_ = wq + (size_t)(tap) * 4096;                      \
    _Pragma("unroll")                                                           \
    for (int i = 0; i < 8; ++i)                                                 \
      bank[i] = *(const bf16x8*)(wt_ + i * 512);                                \
  }

#define LOADBX(dst, dy, dx, ks)                                                 \
  {                                                                             \
    _Pragma("unroll")                                                           \
    for (int f = 0; f < 4; ++f) {                                               \
      int rowp = f >> 1, ch = f & 1;                                            \
      int sp = (wave * 2 + rowp + (dy)) * 34 + ch * 16 + px + (dx);             \
      int slot = (((((ks) << 2) | kg) ^ (gl + rowp + (dy) + (dx))) & 7);        \
      dst[f] = *(const bf16x8*)(xs + sp * 128 + (slot << 4));                   \
    }                                                                           \
  }

  // consume one tap from register bank: 8 LDS reads -> 32 MFMA
#define TAP(bank, dy, dx)                                                       \
  {                                                                             \
    bf16x8 bx0[4], bx1[4];                                                      \
    LOADBX(bx0, dy, dx, 0);                                                     \
    LOADBX(bx1, dy, dx, 1);                                                     \
    __builtin_amdgcn_s_setprio(1);                                              \
    _Pragma("unroll")                                                           \
    for (int ot = 0; ot < 4; ++ot)                                              \
      _Pragma("unroll")                                                         \
      for (int f = 0; f < 4; ++f)                                               \
        acc[ot][f] = __builtin_amdgcn_mfma_f32_16x16x32_bf16(bank[ot], bx0[f],  \
                                                             acc[ot][f], 0, 0, 0); \
    _Pragma("unroll")                                                           \
    for (int ot = 0; ot < 4; ++ot)                                              \
      _Pragma("unroll")                                                         \
      for (int f = 0; f < 4; ++f)                                               \
        acc[ot][f] = __builtin_amdgcn_mfma_f32_16x16x32_bf16(bank[4 + ot], bx1[f], \
                                                             acc[ot][f], 0, 0, 0); \
    __builtin_amdgcn_s_setprio(0);                                              \
  }

#define EPILOGUE(eidx)                                                          \
  {                                                                             \
    float gA = probs[((size_t)(b * EE + (eidx)) * NP + pi) * NP + pj0];         \
    float gB = probs[((size_t)(b * EE + (eidx)) * NP + pi) * NP + pj0 + 1];     \
    _Pragma("unroll")                                                           \
    for (int ot = 0; ot < 4; ++ot) {                                            \
      f32x4 bias = *(const f32x4*)(be + (eidx) * OO + ot * 16 + kg * 4);        \
      _Pragma("unroll")                                                         \
      for (int f = 0; f < 4; ++f) {                                             \
        float gt = (f & 1) ? gB : gA;                                           \
        _Pragma("unroll")                                                       \
        for (int r = 0; r < 4; ++r) {                                           \
          outacc[ot][f][r] += gt * fmaxf(acc[ot][f][r] + bias[r], 0.f);         \
          acc[ot][f][r] = 0.f;                                                  \
        }                                                                       \
      }                                                                         \
    }                                                                           \
  }

#define ADVANCE()                                                               \
  {                                                                             \
    if (t9 == 8) { EPILOGUE(e); ++e; t9 = 0; dy = 0; dx = 0; }                  \
    else { ++t9; if (++dx == 3) { dx = 0; ++dy; } }                             \
  }

  bf16x8 awA[8], awB[8];
  LOADW(awA, 0);
  LOADW(awB, 1);

  int e = 0, t9 = 0, dy = 0, dx = 0;
  for (int u = 0; u < 36; ++u) {
    // consume tap 2u (bank A), then refill A with tap 2u+2
    TAP(awA, dy, dx);
    if (u < 35) LOADW(awA, 2 * u + 2);
    ADVANCE();
    // consume tap 2u+1 (bank B), then refill B with tap 2u+3
    TAP(awB, dy, dx);
    if (u < 35) LOADW(awB, 2 * u + 3);
    ADVANCE();
  }

  // ---- store: lane holds o = ot*16+kg*4+r, col = w0 + ch*16 + px ----
#pragma unroll
  for (int ot = 0; ot < 4; ++ot) {
#pragma unroll
    for (int f = 0; f < 4; ++f) {
      int rowp = f >> 1, ch = f & 1;
      int o = ot * 16 + kg * 4;
      int h = h0 + wave * 2 + rowp;
      float* op = out + ((size_t)(b * OO + o) * HH + h) * WW + w0 + ch * 16 + px;
#pragma unroll
      for (int r = 0; r < 4; ++r)
        op[(size_t)r * HH * WW] = outacc[ot][f][r];
    }
  }
#undef LOADW
#undef LOADBX
#undef TAP
#undef EPILOGUE
#undef ADVANCE
}

extern "C" void kernel_launch(void* const* d_in, const int* in_sizes, int n_in,
                              void* d_out, int out_size, void* d_ws, size_t ws_size,
                              hipStream_t stream) {
  const float* x  = (const float*)d_in[0];
  const float* We = (const float*)d_in[1];
  const float* be = (const float*)d_in[2];
  const float* W1 = (const float*)d_in[3];
  const float* b1 = (const float*)d_in[4];
  const float* W2 = (const float*)d_in[5];
  const float* b2 = (const float*)d_in[6];
  float* out = (float*)d_out;

  float* probs = (float*)d_ws;                                  // 16 KB
  unsigned short* wpk = (unsigned short*)((char*)d_ws + 16384); // 576 KB packed weights

  prep_kernel<<<dim3(512 + (EE * 9 * OO * CC + 255) / 256), dim3(256), 0, stream>>>(
      x, W1, b1, W2, b2, We, probs, wpk);
  conv_moe<<<dim3(16 * 4, BB), dim3(256), 0, stream>>>(x, wpk, be, probs, out);
}